// Round 12
// baseline (49.770 us; speedup 1.0000x reference)
//
#include <hip/hip_runtime.h>
#include <hip/hip_bf16.h>
#include <math.h>

#define L_SEQ 1024
#define DIMSZ 512
#define NH 8
#define ND 64
#define NB 2
#define CHUNK 64
#define NC (L_SEQ / CHUNK)   // 16
#define BHTOT (NB * NH)      // 16
#define MTOT 2048
#define NTOT 1536
#define KEFF 512
#define BM 64
#define BN 96

typedef __attribute__((ext_vector_type(8))) _Float16 f16x8;
typedef __attribute__((ext_vector_type(4))) float f32x4;

#define GLD16(g, l) __builtin_amdgcn_global_load_lds( \
    (const __attribute__((address_space(1))) unsigned int*)(g), \
    (__attribute__((address_space(3))) unsigned int*)(l), 16, 0, 0)

__device__ static inline unsigned short f2h(float f) {
    union { _Float16 h; unsigned short u; } x;
    x.h = (_Float16)f;
    return x.u;
}
__device__ static inline float h2f(unsigned short u) {
    union { unsigned short u; _Float16 h; } x;
    x.u = u;
    return (float)x.h;
}
__device__ static inline _Float16 u2h(unsigned short u) {
    union { unsigned short u; _Float16 h; } x;
    x.u = u;
    return x.h;
}
__device__ static inline unsigned packh2(float a, float b) {
    return (unsigned)f2h(a) | ((unsigned)f2h(b) << 16);
}

// ---------------------------------------------------------------------------
// pack: [0,1024)    A[n][k] = fp16(x)            (2048 x 512)
//       [1024,1792) B[which*512+o][k] = fp16(W)  (1536 x 512)
//       [1792,1800) lcT[h][e*64+d] = packh2(lc[h][d][e])  (transposed, packed)
// ---------------------------------------------------------------------------
__global__ __launch_bounds__(256) void pack_kernel(
    const float* __restrict__ x,
    const float* __restrict__ wq, const float* __restrict__ wk, const float* __restrict__ wv,
    const float* __restrict__ lc_re, const float* __restrict__ lc_im,
    unsigned short* __restrict__ A, unsigned short* __restrict__ Bm,
    unsigned* __restrict__ lcT)
{
    __shared__ unsigned T[64][65];
    const int bid = blockIdx.x;
    const int tid = threadIdx.x;
    if (bid < 1024) {
        const int i = bid * 256 + tid;
        const int n  = i >> 7;
        const int kq = (i & 127) << 2;
        const float4 xv = *(const float4*)(x + (size_t)n * DIMSZ + kq);
        *(ushort4*)(A + (size_t)n * KEFF + kq) =
            make_ushort4(f2h(xv.x), f2h(xv.y), f2h(xv.z), f2h(xv.w));
    } else if (bid < 1792) {
        const int idx = bid - 1024;
        const int which = idx >> 8;
        const float* w = which == 0 ? wq : (which == 1 ? wk : wv);
        const int i = (idx & 255) * 256 + tid;
        const int o  = i >> 7;
        const int kq = (i & 127) << 2;
        const float4 wv4 = *(const float4*)(w + (size_t)o * DIMSZ + kq);
        *(ushort4*)(Bm + (size_t)(which * 512 + o) * KEFF + kq) =
            make_ushort4(f2h(wv4.x), f2h(wv4.y), f2h(wv4.z), f2h(wv4.w));
    } else {
        const int h = bid - 1792;
        const int e = tid & 63;
        #pragma unroll
        for (int i = 0; i < 16; ++i) {
            const int d = i*4 + (tid >> 6);
            T[e][d] = packh2(lc_re[h*4096 + d*64 + e], lc_im[h*4096 + d*64 + e]);
        }
        __syncthreads();
        const int d = tid & 63;
        #pragma unroll
        for (int i = 0; i < 16; ++i) {
            const int e2 = i*4 + (tid >> 6);
            lcT[h*4096 + e2*64 + d] = T[e2][d];
        }
    }
}

// ---------------------------------------------------------------------------
// GEMM: C[2048x1536] = A x B^T, MFMA 16x16x32 f16, K=512.  Outputs fp16.
// ---------------------------------------------------------------------------
__global__ __launch_bounds__(256) void gemm_kernel(
    const unsigned short* __restrict__ A, const unsigned short* __restrict__ Bm,
    const float* __restrict__ bq, const float* __restrict__ bk, const float* __restrict__ bv,
    unsigned short* __restrict__ qo, unsigned short* __restrict__ ko,
    unsigned short* __restrict__ vo)
{
    __shared__ __align__(16) char lds[2][20480];   // [A 8KB | B 12KB] x 2
    const int tid  = threadIdx.x;
    const int lane = tid & 63;
    const int wave = tid >> 6;

    const int bid = blockIdx.y * 32 + blockIdx.x;
    const int sw  = (bid & 7) * 64 + (bid >> 3);
    const int row0 = (sw >> 4) * BM;
    const int col0 = (sw & 15) * BN;
    const int wr = wave >> 1, wc = wave & 1;

    const int srow = tid >> 3;
    const int sin  = (tid & 7) << 4;
    size_t goffA[2], goffB[3];
    #pragma unroll
    for (int c = 0; c < 2; ++c) {
        const int row = c * 32 + srow;
        const int swz = sin ^ ((row & 7) << 4);
        goffA[c] = (size_t)(row0 + row) * (KEFF * 2) + swz;
    }
    #pragma unroll
    for (int c = 0; c < 3; ++c) {
        const int row = c * 32 + srow;
        const int swz = sin ^ ((row & 7) << 4);
        goffB[c] = (size_t)(col0 + row) * (KEFF * 2) + swz;
    }
    const int ldst = tid * 16;
    const char* Abyte = (const char*)A;
    const char* Bbyte = (const char*)Bm;

    f32x4 acc[2][3];
    const f32x4 zf = {0.f, 0.f, 0.f, 0.f};
    #pragma unroll
    for (int m = 0; m < 2; ++m)
        #pragma unroll
        for (int n = 0; n < 3; ++n) acc[m][n] = zf;

    auto stage = [&](int buf, int t) {
        char* la = &lds[buf][0];
        char* lb = &lds[buf][8192];
        const size_t kb = (size_t)t * 128;
        #pragma unroll
        for (int c = 0; c < 2; ++c)
            GLD16(Abyte + goffA[c] + kb, la + c * 4096 + ldst);
        #pragma unroll
        for (int c = 0; c < 3; ++c)
            GLD16(Bbyte + goffB[c] + kb, lb + c * 4096 + ldst);
    };

    const int rl = lane & 15;
    const int kg = lane >> 4;
    const int rswz = (rl & 7) << 4;

    auto compute = [&](int buf) {
        const char* la = &lds[buf][0];
        const char* lb = &lds[buf][8192];
        #pragma unroll
        for (int ks = 0; ks < 2; ++ks) {
            f16x8 av[2], bvv[3];
            #pragma unroll
            for (int m = 0; m < 2; ++m) {
                const int row = wr * 32 + m * 16 + rl;
                const int addr = (row * 128 + ks * 64 + kg * 16) ^ rswz;
                av[m] = *(const f16x8*)(la + addr);
            }
            #pragma unroll
            for (int n = 0; n < 3; ++n) {
                const int row = wc * 48 + n * 16 + rl;
                const int addr = (row * 128 + ks * 64 + kg * 16) ^ rswz;
                bvv[n] = *(const f16x8*)(lb + addr);
            }
            #pragma unroll
            for (int m = 0; m < 2; ++m)
                #pragma unroll
                for (int n = 0; n < 3; ++n)
                    acc[m][n] = __builtin_amdgcn_mfma_f32_16x16x32_f16(
                        av[m], bvv[n], acc[m][n], 0, 0, 0);
        }
    };

    stage(0, 0);
    __syncthreads();
    const int NT = KEFF / 64;   // 8
    for (int t = 0; t < NT; ++t) {
        if (t + 1 < NT) stage((t + 1) & 1, t + 1);
        compute(t & 1);
        __syncthreads();
    }

    #pragma unroll
    for (int n = 0; n < 3; ++n) {
        const int cabs = col0 + wc * 48 + n * 16 + rl;
        const int which = cabs >> 9;
        const int cl = cabs & 511;
        const float* bias = which == 0 ? bq : (which == 1 ? bk : bv);
        unsigned short* outp = which == 0 ? qo : (which == 1 ? ko : vo);
        const float bs = bias[cl];
        #pragma unroll
        for (int m = 0; m < 2; ++m) {
            const int rb = row0 + wr * 32 + m * 16 + kg * 4;
            #pragma unroll
            for (int r = 0; r < 4; ++r)
                outp[(size_t)(rb + r) * DIMSZ + cl] = f2h(acc[m][n][r] + bs);
        }
    }
}

// ---------------------------------------------------------------------------
// chunk_kv (MFMA): KV^T[e][d] = sum_j (v[j,e] amp^{63-j}) * khat[j,d]
// Output kvB TRANSPOSED [e][d], PACKED fp16 (re | im<<16).  Write-once.
// ---------------------------------------------------------------------------
__global__ __launch_bounds__(256) void chunk_kv_kernel(
    const unsigned short* __restrict__ k, const unsigned short* __restrict__ v,
    const float* __restrict__ ph_re, const float* __restrict__ ph_im,
    const float* __restrict__ ampl, unsigned* __restrict__ kvB)
{
    __shared__ __align__(16) _Float16 KTR[64][72];
    __shared__ __align__(16) _Float16 KTI[64][72];
    __shared__ __align__(16) _Float16 VWT[64][72];

    const int bhc = blockIdx.x;
    const int c  = bhc & (NC - 1);
    const int bh = bhc >> 4;
    const int b = bh >> 3, h = bh & 7;
    const int tid = threadIdx.x;
    const int lane = tid & 63, w = tid >> 6;
    const int rl = lane & 15, kg = lane >> 4;

    const float la = -logf(1.0f + expf(-ampl[h]));
    const float th = atan2f(ph_im[h*ND + lane], ph_re[h*ND + lane]);

    #pragma unroll
    for (int jj = 0; jj < 16; ++jj) {
        const int j = w*16 + jj;
        const size_t off = ((size_t)(b*L_SEQ + c*CHUNK + j)) * DIMSZ + h*ND + lane;
        const float kk = h2f(k[off]), vv = h2f(v[off]);
        const float p = (float)(CHUNK - 1 - j);
        const float ap = expf(la * p);
        float s, ct; sincosf(th * p, &s, &ct);
        KTR[lane][j] = (_Float16)(kk * ct);
        KTI[lane][j] = (_Float16)(kk * s);
        VWT[lane][j] = (_Float16)(vv * ap);
    }
    __syncthreads();

    unsigned* dst = kvB + (size_t)bhc * (ND*ND);
    const f32x4 zf = {0.f, 0.f, 0.f, 0.f};
    #pragma unroll
    for (int i = 0; i < 4; ++i) {
        const int mt = w, nt = i;            // e-tile = wave, d-tile = i
        f32x4 aR = zf, aI = zf;
        #pragma unroll
        for (int ks = 0; ks < 2; ++ks) {
            const f16x8 av = *(const f16x8*)&VWT[mt*16 + rl][ks*32 + kg*8];
            const f16x8 br = *(const f16x8*)&KTR[nt*16 + rl][ks*32 + kg*8];
            const f16x8 bi = *(const f16x8*)&KTI[nt*16 + rl][ks*32 + kg*8];
            aR = __builtin_amdgcn_mfma_f32_16x16x32_f16(av, br, aR, 0, 0, 0);
            aI = __builtin_amdgcn_mfma_f32_16x16x32_f16(av, bi, aI, 0, 0, 0);
        }
        const int d = nt*16 + rl;
        #pragma unroll
        for (int r = 0; r < 4; ++r) {
            const int e = mt*16 + kg*4 + r;
            dst[e*ND + d] = packh2(aR[r], aI[r]);
        }
    }
}

// ---------------------------------------------------------------------------
// chunk_out (MFMA, inline prefix-scan): 512 blocks (bhc*2+half), 32 rows each.
// B_c computed in-block: B_c = sum_{p=0}^{c-1} L^p KV_{c-1-p} + L^c lcT,
// L = amp^64 e^{i 64 theta_d}, d = lane for every packed element this thread
// touches (idx = ii*256+tid).  fp32 accumulate, exact w-power recurrence.
// ---------------------------------------------------------------------------
__global__ __launch_bounds__(256) void chunk_out_kernel(
    const unsigned short* __restrict__ q, const unsigned short* __restrict__ k,
    const unsigned short* __restrict__ v, const unsigned* __restrict__ kvB,
    const unsigned* __restrict__ lcT,
    const float* __restrict__ ph_re, const float* __restrict__ ph_im,
    const float* __restrict__ ampl, float* __restrict__ out)
{
    __shared__ __align__(16) _Float16 QhR[32][72], QhI[32][72];
    __shared__ __align__(16) _Float16 QcR[32][72], QcIn[32][72];
    __shared__ __align__(16) _Float16 KhR[64][72], KhI[64][72];   // -> BTR/BTI
    __shared__ __align__(16) _Float16 VT[64][72];
    __shared__ __align__(16) _Float16 SA[32][72];
    __shared__ float apw[80];

    const int half = blockIdx.x & 1;
    const int bhc = blockIdx.x >> 1;
    const int c  = bhc & (NC - 1);
    const int bh = bhc >> 4;
    const int b = bh >> 3, h = bh & 7;
    const int tid = threadIdx.x;
    const int lane = tid & 63, w = tid >> 6;
    const int rl = lane & 15, kg = lane >> 4;
    const int mt = w >> 1;                    // output row-tile of this wave

    const float la = -logf(1.0f + expf(-ampl[h]));
    if (tid < 72) apw[tid] = expf(la * (float)tid);
    const float th = atan2f(ph_im[h*ND + lane], ph_re[h*ND + lane]);
    float sth_, cth_; sincosf(th, &sth_, &cth_);

    // ---- inline prefix scan: B_c for this block's (bh, c) ----
    float2 bacc[16];
    #pragma unroll
    for (int ii = 0; ii < 16; ++ii) bacc[ii] = make_float2(0.f, 0.f);
    {
        const float ampC = expf(la * (float)CHUNK);
        float s64, c64; sincosf(th * (float)CHUNK, &s64, &c64);
        const float Lr = ampC * c64, Li = ampC * s64;    // Lambda for d=lane
        float wr = 1.f, wi = 0.f;
        for (int p = 0; p < c; ++p) {
            const unsigned* src = kvB + (size_t)(bh*NC + (c-1-p)) * (ND*ND);
            #pragma unroll
            for (int ii = 0; ii < 16; ++ii) {
                const unsigned u = src[ii*256 + tid];
                const float tr = h2f((unsigned short)(u & 0xffffu));
                const float ti = h2f((unsigned short)(u >> 16));
                bacc[ii].x += wr*tr - wi*ti;
                bacc[ii].y += wr*ti + wi*tr;
            }
            const float nwr = wr*Lr - wi*Li;
            wi = wr*Li + wi*Lr; wr = nwr;
        }
        const unsigned* lsrc = lcT + h*4096;
        #pragma unroll
        for (int ii = 0; ii < 16; ++ii) {
            const unsigned u = lsrc[ii*256 + tid];
            const float tr = h2f((unsigned short)(u & 0xffffu));
            const float ti = h2f((unsigned short)(u >> 16));
            bacc[ii].x += wr*tr - wi*ti;
            bacc[ii].y += wr*ti + wi*tr;
        }
    }

    // stage Qh / Qc (rows of this half)
    #pragma unroll
    for (int jj = 0; jj < 8; ++jj) {
        const int row = w*8 + jj;
        const int jabs = half*32 + row;
        const size_t off = ((size_t)(b*L_SEQ + c*CHUNK + jabs)) * DIMSZ + h*ND + lane;
        const float qq = h2f(q[off]);
        float s, cc; sincosf(th * (float)jabs, &s, &cc);
        const float qhr = qq * cc, qhi = qq * s;
        QhR[row][lane] = (_Float16)qhr;
        QhI[row][lane] = (_Float16)qhi;
        QcR[row][lane]  = (_Float16)(qhr*cth_ - qhi*sth_);
        QcIn[row][lane] = (_Float16)(-(qhr*sth_ + qhi*cth_));
    }
    // stage Kh (rows this half needs), V transposed (zero unused cols)
    #pragma unroll
    for (int jj = 0; jj < 16; ++jj) {
        const int j = w*16 + jj;
        if (half == 0 && j >= 32) {
            VT[lane][j] = (_Float16)0.f;      // KhR/KhI garbage masked later
        } else {
            const size_t off = ((size_t)(b*L_SEQ + c*CHUNK + j)) * DIMSZ + h*ND + lane;
            const float kk = h2f(k[off]), vv = h2f(v[off]);
            float s, cc; sincosf(th * (float)j, &s, &cc);
            KhR[j][lane] = (_Float16)(kk * cc);
            KhI[j][lane] = (_Float16)(kk * s);
            VT[lane][j]  = (_Float16)vv;
        }
    }
    __syncthreads();

    // ---- scores ----
    const f32x4 zf = {0.f, 0.f, 0.f, 0.f};
    f32x4 sacc[2] = {zf, zf};
    #pragma unroll
    for (int t = 0; t < 2; ++t) {
        const int nt = (w & 1)*2 + t;
        #pragma unroll
        for (int ks = 0; ks < 2; ++ks) {
            const f16x8 aR = *(const f16x8*)&QhR[mt*16 + rl][ks*32 + kg*8];
            const f16x8 bR = *(const f16x8*)&KhR[nt*16 + rl][ks*32 + kg*8];
            sacc[t] = __builtin_amdgcn_mfma_f32_16x16x32_f16(aR, bR, sacc[t], 0, 0, 0);
            const f16x8 aI = *(const f16x8*)&QhI[mt*16 + rl][ks*32 + kg*8];
            const f16x8 bI = *(const f16x8*)&KhI[nt*16 + rl][ks*32 + kg*8];
            sacc[t] = __builtin_amdgcn_mfma_f32_16x16x32_f16(aI, bI, sacc[t], 0, 0, 0);
        }
    }
    __syncthreads();   // everyone done reading Kh

    // ---- SA = mask(scores) fp16;  B -> Kh space ----
    #pragma unroll
    for (int t = 0; t < 2; ++t) {
        const int nt = (w & 1)*2 + t;
        #pragma unroll
        for (int r = 0; r < 4; ++r) {
            const int rowm = mt*16 + kg*4 + r;
            const int jabs = half*32 + rowm;
            const int jp = nt*16 + rl;
            const int delta = jabs - jp;
            const float val = (delta >= 0) ? sacc[t][r] * apw[delta] : 0.0f;
            SA[rowm][jp] = (_Float16)val;
        }
    }
    #pragma unroll
    for (int ii = 0; ii < 16; ++ii) {
        const int e = ii*4 + w;     // idx = ii*256 + tid -> e = ii*4 + w, d = lane
        KhR[e][lane] = (_Float16)bacc[ii].x;
        KhI[e][lane] = (_Float16)bacc[ii].y;
    }
    __syncthreads();

    // ---- PV + cross ----
    #pragma unroll
    for (int t = 0; t < 2; ++t) {
        const int nt = (w & 1)*2 + t;   // e-tile
        f32x4 accO = zf, accC = zf;
        #pragma unroll
        for (int ks = 0; ks < 2; ++ks) {
            const f16x8 aS = *(const f16x8*)&SA[mt*16 + rl][ks*32 + kg*8];
            const f16x8 bV = *(const f16x8*)&VT[nt*16 + rl][ks*32 + kg*8];
            accO = __builtin_amdgcn_mfma_f32_16x16x32_f16(aS, bV, accO, 0, 0, 0);
            const f16x8 aCR = *(const f16x8*)&QcR[mt*16 + rl][ks*32 + kg*8];
            const f16x8 bBR = *(const f16x8*)&KhR[nt*16 + rl][ks*32 + kg*8];
            accC = __builtin_amdgcn_mfma_f32_16x16x32_f16(aCR, bBR, accC, 0, 0, 0);
            const f16x8 aCI = *(const f16x8*)&QcIn[mt*16 + rl][ks*32 + kg*8];
            const f16x8 bBI = *(const f16x8*)&KhI[nt*16 + rl][ks*32 + kg*8];
            accC = __builtin_amdgcn_mfma_f32_16x16x32_f16(aCI, bBI, accC, 0, 0, 0);
        }
        const int e = nt*16 + rl;
        #pragma unroll
        for (int r = 0; r < 4; ++r) {
            const int rowm = mt*16 + kg*4 + r;
            const int jabs = half*32 + rowm;
            const float cs = apw[jabs + 1];
            out[((size_t)(b*L_SEQ + c*CHUNK + jabs)) * DIMSZ + h*ND + e] =
                accO[r] + cs * accC[r];
        }
    }
}

// ---------------------------------------------------------------------------
extern "C" void kernel_launch(void* const* d_in, const int* in_sizes, int n_in,
                              void* d_out, int out_size, void* d_ws, size_t ws_size,
                              hipStream_t stream)
{
    const float* x     = (const float*)d_in[0];
    const float* wq_w  = (const float*)d_in[1];
    const float* wq_b  = (const float*)d_in[2];
    const float* wk_w  = (const float*)d_in[3];
    const float* wk_b  = (const float*)d_in[4];
    const float* wv_w  = (const float*)d_in[5];
    const float* wv_b  = (const float*)d_in[6];
    const float* ph_re = (const float*)d_in[7];
    const float* ph_im = (const float*)d_in[8];
    const float* ampl  = (const float*)d_in[9];
    const float* lc_re = (const float*)d_in[10];
    const float* lc_im = (const float*)d_in[11];
    float* out = (float*)d_out;

    char* wsb = (char*)d_ws;
    const size_t MB = 1024 * 1024;
    unsigned short* q = (unsigned short*)(wsb + 0);          // 2 MB (fp16)
    unsigned short* k = (unsigned short*)(wsb + 2 * MB);     // 2 MB
    unsigned short* v = (unsigned short*)(wsb + 4 * MB);     // 2 MB
    unsigned* kvB = (unsigned*)(wsb + 8 * MB);               // 4 MB (packed h2)
    unsigned short* Apk = (unsigned short*)(wsb + 13 * MB);  // 2 MB
    unsigned short* Bpk = (unsigned short*)(wsb + 16 * MB);  // 1.5 MB
    unsigned* lcT = (unsigned*)(wsb + 18 * MB);              // 128 KB

    pack_kernel<<<1800, 256, 0, stream>>>(
        x, wq_w, wk_w, wv_w, lc_re, lc_im, Apk, Bpk, lcT);
    gemm_kernel<<<dim3(MTOT / BM, NTOT / BN), 256, 0, stream>>>(
        Apk, Bpk, wq_b, wk_b, wv_b, q, k, v);
    chunk_kv_kernel<<<BHTOT * NC, 256, 0, stream>>>(k, v, ph_re, ph_im, ampl, kvB);
    chunk_out_kernel<<<BHTOT * NC * 2, 256, 0, stream>>>(
        q, k, v, kvB, lcT, ph_re, ph_im, ampl, out);
}

// Round 13
// 41.354 us; speedup vs baseline: 1.2035x; 1.2035x over previous
//
#include <hip/hip_runtime.h>
#include <hip/hip_bf16.h>
#include <math.h>

#define L_SEQ 1024
#define DIMSZ 512
#define NH 8
#define ND 64
#define NB 2
#define CHUNK 64
#define NC (L_SEQ / CHUNK)   // 16
#define BHTOT (NB * NH)      // 16
#define MTOT 2048
#define KEFF 512
#define BM 64
#define BN 128

typedef __attribute__((ext_vector_type(8))) _Float16 f16x8;
typedef __attribute__((ext_vector_type(4))) float f32x4;

#define GLD16(g, l) __builtin_amdgcn_global_load_lds( \
    (const __attribute__((address_space(1))) unsigned int*)(g), \
    (__attribute__((address_space(3))) unsigned int*)(l), 16, 0, 0)

__device__ static inline unsigned short f2h(float f) {
    union { _Float16 h; unsigned short u; } x;
    x.h = (_Float16)f;
    return x.u;
}
__device__ static inline float h2f(unsigned short u) {
    union { unsigned short u; _Float16 h; } x;
    x.u = u;
    return (float)x.h;
}
__device__ static inline _Float16 u2h(unsigned short u) {
    union { unsigned short u; _Float16 h; } x;
    x.u = u;
    return x.h;
}
__device__ static inline unsigned packh2(float a, float b) {
    return (unsigned)f2h(a) | ((unsigned)f2h(b) << 16);
}

// ---------------------------------------------------------------------------
// pack: [0,1024)    A[n][k] = fp16(x)                    (2048 x 512)
//       [1024,1792) B~ rows: q -> o ; k -> 512+(o>>6)*128+(o&63) ;
//                             v -> 576+(o>>6)*128+(o&63)   (per-head [k|v])
//       [1792,1800) lcT[h][e*64+d] = packh2(lc[h][d][e])
// ---------------------------------------------------------------------------
__global__ __launch_bounds__(256) void pack_kernel(
    const float* __restrict__ x,
    const float* __restrict__ wq, const float* __restrict__ wk, const float* __restrict__ wv,
    const float* __restrict__ lc_re, const float* __restrict__ lc_im,
    unsigned short* __restrict__ A, unsigned short* __restrict__ Bm,
    unsigned* __restrict__ lcT)
{
    __shared__ unsigned T[64][65];
    const int bid = blockIdx.x;
    const int tid = threadIdx.x;
    if (bid < 1024) {
        const int i = bid * 256 + tid;
        const int n  = i >> 7;
        const int kq = (i & 127) << 2;
        const float4 xv = *(const float4*)(x + (size_t)n * DIMSZ + kq);
        *(ushort4*)(A + (size_t)n * KEFF + kq) =
            make_ushort4(f2h(xv.x), f2h(xv.y), f2h(xv.z), f2h(xv.w));
    } else if (bid < 1792) {
        const int idx = bid - 1024;
        const int which = idx >> 8;
        const float* w = which == 0 ? wq : (which == 1 ? wk : wv);
        const int i = (idx & 255) * 256 + tid;
        const int o  = i >> 7;
        const int kq = (i & 127) << 2;
        const float4 wv4 = *(const float4*)(w + (size_t)o * DIMSZ + kq);
        const int row = (which == 0) ? o
                      : 512 + (which - 1) * 64 + (o >> 6) * 128 + (o & 63);
        *(ushort4*)(Bm + (size_t)row * KEFF + kq) =
            make_ushort4(f2h(wv4.x), f2h(wv4.y), f2h(wv4.z), f2h(wv4.w));
    } else {
        const int h = bid - 1792;
        const int e = tid & 63;
        #pragma unroll
        for (int i = 0; i < 16; ++i) {
            const int d = i*4 + (tid >> 6);
            T[e][d] = packh2(lc_re[h*4096 + d*64 + e], lc_im[h*4096 + d*64 + e]);
        }
        __syncthreads();
        const int d = tid & 63;
        #pragma unroll
        for (int i = 0; i < 16; ++i) {
            const int e2 = i*4 + (tid >> 6);
            lcT[h*4096 + e2*64 + d] = T[e2][d];
        }
    }
}

// ---------------------------------------------------------------------------
// gemm_kv: 384 blocks.  sw<128: q-block (cols panel*128..+128 of q).
//          sw>=128: kv-block for (mtile, h) = K-tile + V-tile of head h,
//          then fused chunk_kv for (b = mtile>>4, h, c = mtile&15):
//          overlay dead GEMM LDS, re-stage k/v from regs, rotate/decay,
//          MFMA KV^T -> packed-fp16 kvB.
// ---------------------------------------------------------------------------
__global__ __launch_bounds__(256) void gemm_kv_kernel(
    const unsigned short* __restrict__ A, const unsigned short* __restrict__ Bm,
    const float* __restrict__ bq, const float* __restrict__ bk, const float* __restrict__ bv,
    const float* __restrict__ ph_re, const float* __restrict__ ph_im,
    const float* __restrict__ ampl,
    unsigned short* __restrict__ qo, unsigned short* __restrict__ ko,
    unsigned short* __restrict__ vo, unsigned* __restrict__ kvB)
{
    __shared__ __align__(16) char lds[49152];   // gemm: 2 x [A 8KB | B 16KB]
    const int tid  = threadIdx.x;
    const int lane = tid & 63;
    const int wave = tid >> 6;

    const int bid0 = blockIdx.x;                 // 384 = 8 XCD x 48
    const int sw = (bid0 & 7) * 48 + (bid0 >> 3);
    const bool isQ = sw < 128;
    int mtile, brow0, h = 0, panel = 0;
    if (isQ) { panel = sw & 3; mtile = sw >> 2; brow0 = panel * 128; }
    else     { const int r = sw - 128; h = r & 7; mtile = r >> 3; brow0 = 512 + h * 128; }
    const int row0 = mtile * 64;
    const int wr = wave >> 1, wc = wave & 1;     // wave tile 32 x 64

    const int srow = tid >> 3;
    const int sin  = (tid & 7) << 4;
    size_t goffA[2], goffB[4];
    #pragma unroll
    for (int c = 0; c < 2; ++c) {
        const int row = c * 32 + srow;
        const int swz = sin ^ ((row & 7) << 4);
        goffA[c] = (size_t)(row0 + row) * (KEFF * 2) + swz;
    }
    #pragma unroll
    for (int c = 0; c < 4; ++c) {
        const int row = c * 32 + srow;
        const int swz = sin ^ ((row & 7) << 4);
        goffB[c] = (size_t)(brow0 + row) * (KEFF * 2) + swz;
    }
    const int ldst = tid * 16;
    const char* Abyte = (const char*)A;
    const char* Bbyte = (const char*)Bm;

    f32x4 acc[2][4];
    const f32x4 zf = {0.f, 0.f, 0.f, 0.f};
    #pragma unroll
    for (int m = 0; m < 2; ++m)
        #pragma unroll
        for (int n = 0; n < 4; ++n) acc[m][n] = zf;

    auto stage = [&](int buf, int t) {
        char* la = lds + buf * 24576;
        char* lb = la + 8192;
        const size_t kb = (size_t)t * 128;
        #pragma unroll
        for (int c = 0; c < 2; ++c)
            GLD16(Abyte + goffA[c] + kb, la + c * 4096 + ldst);
        #pragma unroll
        for (int c = 0; c < 4; ++c)
            GLD16(Bbyte + goffB[c] + kb, lb + c * 4096 + ldst);
    };

    const int rl = lane & 15;
    const int kg = lane >> 4;
    const int rswz = (rl & 7) << 4;

    auto compute = [&](int buf) {
        const char* la = lds + buf * 24576;
        const char* lb = la + 8192;
        #pragma unroll
        for (int ks = 0; ks < 2; ++ks) {
            f16x8 av[2], bvv[4];
            #pragma unroll
            for (int m = 0; m < 2; ++m) {
                const int row = wr * 32 + m * 16 + rl;
                const int addr = (row * 128 + ks * 64 + kg * 16) ^ rswz;
                av[m] = *(const f16x8*)(la + addr);
            }
            #pragma unroll
            for (int n = 0; n < 4; ++n) {
                const int row = wc * 64 + n * 16 + rl;
                const int addr = (row * 128 + ks * 64 + kg * 16) ^ rswz;
                bvv[n] = *(const f16x8*)(lb + addr);
            }
            #pragma unroll
            for (int m = 0; m < 2; ++m)
                #pragma unroll
                for (int n = 0; n < 4; ++n)
                    acc[m][n] = __builtin_amdgcn_mfma_f32_16x16x32_f16(
                        av[m], bvv[n], acc[m][n], 0, 0, 0);
        }
    };

    stage(0, 0);
    __syncthreads();
    const int NT = KEFF / 64;   // 8
    for (int t = 0; t < NT; ++t) {
        if (t + 1 < NT) stage((t + 1) & 1, t + 1);
        compute(t & 1);
        __syncthreads();
    }
    // all GEMM LDS dead from here on

    if (isQ) {
        #pragma unroll
        for (int n = 0; n < 4; ++n) {
            const int cabs = panel * 128 + wc * 64 + n * 16 + rl;
            const float bs = bq[cabs];
            #pragma unroll
            for (int m = 0; m < 2; ++m) {
                const int rb = row0 + wr * 32 + m * 16 + kg * 4;
                #pragma unroll
                for (int r = 0; r < 4; ++r)
                    qo[(size_t)(rb + r) * DIMSZ + cabs] = f2h(acc[m][n][r] + bs);
            }
        }
        return;
    }

    // ---- kv-block epilogue: global store + raw LDS stage (overlay) ----
    _Float16 (*KTR)[72] = (_Float16(*)[72])(lds);            //  9216 B
    _Float16 (*KTI)[72] = (_Float16(*)[72])(lds + 9216);     //  9216 B
    _Float16 (*VWT)[72] = (_Float16(*)[72])(lds + 18432);    //  9216 B

    unsigned short* outp = wc == 0 ? ko : vo;
    _Float16 (*RAW)[72] = wc == 0 ? KTR : VWT;   // raw k -> KTR, raw v -> VWT
    #pragma unroll
    for (int n = 0; n < 4; ++n) {
        const int cl = h * 64 + n * 16 + rl;
        const float bs = (wc == 0 ? bk : bv)[cl];
        #pragma unroll
        for (int m = 0; m < 2; ++m) {
            const int jb = wr * 32 + m * 16 + kg * 4;
            #pragma unroll
            for (int r = 0; r < 4; ++r) {
                const float val = acc[m][n][r] + bs;
                outp[(size_t)(row0 + jb + r) * DIMSZ + cl] = f2h(val);
                RAW[n * 16 + rl][jb + r] = (_Float16)val;    // [d or e][j]
            }
        }
    }
    __syncthreads();

    // ---- rotate/decay transform (in place; thread owns (d=lane, 16 j's)) ----
    const float la_ = -logf(1.0f + expf(-ampl[h]));
    const float th = atan2f(ph_im[h*ND + lane], ph_re[h*ND + lane]);
    #pragma unroll
    for (int jj = 0; jj < 16; ++jj) {
        const int j = wave * 16 + jj;
        const float p = (float)(CHUNK - 1 - j);
        const float ap = expf(la_ * p);
        float s, ct; sincosf(th * p, &s, &ct);
        const float kk = (float)KTR[lane][j];
        const float vv = (float)VWT[lane][j];
        KTR[lane][j] = (_Float16)(kk * ct);
        KTI[lane][j] = (_Float16)(kk * s);
        VWT[lane][j] = (_Float16)(vv * ap);
    }
    __syncthreads();

    // ---- KV^T MFMA + packed kvB store ----
    const int b = mtile >> 4, c = mtile & 15;
    unsigned* dst = kvB + (size_t)(((b * NH + h) << 4) | c) * (ND * ND);
    #pragma unroll
    for (int i = 0; i < 4; ++i) {
        const int mt = wave, nt = i;         // e-tile = wave, d-tile = i
        f32x4 aR = zf, aI = zf;
        #pragma unroll
        for (int ks = 0; ks < 2; ++ks) {
            const f16x8 av = *(const f16x8*)&VWT[mt*16 + rl][ks*32 + kg*8];
            const f16x8 br = *(const f16x8*)&KTR[nt*16 + rl][ks*32 + kg*8];
            const f16x8 bi = *(const f16x8*)&KTI[nt*16 + rl][ks*32 + kg*8];
            aR = __builtin_amdgcn_mfma_f32_16x16x32_f16(av, br, aR, 0, 0, 0);
            aI = __builtin_amdgcn_mfma_f32_16x16x32_f16(av, bi, aI, 0, 0, 0);
        }
        const int d = nt*16 + rl;
        #pragma unroll
        for (int r = 0; r < 4; ++r) {
            const int e = mt*16 + kg*4 + r;
            dst[e*ND + d] = packh2(aR[r], aI[r]);
        }
    }
}

// ---------------------------------------------------------------------------
// scan (packed fp16, transposed layout, coalesced packed lcT): idx = e*64+d.
// ---------------------------------------------------------------------------
__global__ __launch_bounds__(256) void scan_kernel(
    unsigned* __restrict__ kvB, const unsigned* __restrict__ lcT,
    const float* __restrict__ ph_re, const float* __restrict__ ph_im,
    const float* __restrict__ ampl)
{
    const int gid = blockIdx.x * 256 + threadIdx.x;   // 65536
    const int bh = gid >> 12;
    const int idx = gid & 4095;
    const int h = bh & 7;
    const int d = idx & 63;

    const float th = atan2f(ph_im[h*ND + d], ph_re[h*ND + d]);
    const float la = -logf(1.0f + expf(-ampl[h]));
    const float ampC = expf(la * (float)CHUNK);
    float s, ct; sincosf(th * (float)CHUNK, &s, &ct);
    const float aCr = ampC * ct, aCi = ampC * s;

    unsigned* base = kvB + (size_t)bh * NC * (ND*ND) + idx;
    unsigned tl[NC];
    #pragma unroll
    for (int cc = 0; cc < NC; ++cc) tl[cc] = base[(size_t)cc * (ND*ND)];

    const unsigned lcp = lcT[h*4096 + idx];
    float Sr = h2f((unsigned short)(lcp & 0xffffu));
    float Si = h2f((unsigned short)(lcp >> 16));
    #pragma unroll
    for (int cc = 0; cc < NC; ++cc) {
        base[(size_t)cc * (ND*ND)] = packh2(Sr, Si);
        const float tr = h2f((unsigned short)(tl[cc] & 0xffffu));
        const float ti = h2f((unsigned short)(tl[cc] >> 16));
        const float nr = aCr*Sr - aCi*Si + tr;
        const float ni = aCr*Si + aCi*Sr + ti;
        Sr = nr; Si = ni;
    }
}

// ---------------------------------------------------------------------------
// chunk_out (MFMA): 512 blocks (bhc*2+half), 32 output rows each. (R11)
// ---------------------------------------------------------------------------
__global__ __launch_bounds__(256) void chunk_out_kernel(
    const unsigned short* __restrict__ q, const unsigned short* __restrict__ k,
    const unsigned short* __restrict__ v, const unsigned* __restrict__ Bst,
    const float* __restrict__ ph_re, const float* __restrict__ ph_im,
    const float* __restrict__ ampl, float* __restrict__ out)
{
    __shared__ __align__(16) _Float16 QhR[32][72], QhI[32][72];
    __shared__ __align__(16) _Float16 QcR[32][72], QcIn[32][72];
    __shared__ __align__(16) _Float16 KhR[64][72], KhI[64][72];   // -> BTR/BTI
    __shared__ __align__(16) _Float16 VT[64][72];
    __shared__ __align__(16) _Float16 SA[32][72];
    __shared__ float apw[80];

    const int half = blockIdx.x & 1;
    const int bhc = blockIdx.x >> 1;
    const int c  = bhc & (NC - 1);
    const int bh = bhc >> 4;
    const int b = bh >> 3, h = bh & 7;
    const int tid = threadIdx.x;
    const int lane = tid & 63, w = tid >> 6;
    const int rl = lane & 15, kg = lane >> 4;
    const int mt = w >> 1;

    const float la = -logf(1.0f + expf(-ampl[h]));
    if (tid < 72) apw[tid] = expf(la * (float)tid);
    const float th = atan2f(ph_im[h*ND + lane], ph_re[h*ND + lane]);
    float sth_, cth_; sincosf(th, &sth_, &cth_);

    unsigned breg[16];
    const unsigned* Bb = Bst + (size_t)bhc * (ND*ND);
    #pragma unroll
    for (int ii = 0; ii < 16; ++ii) breg[ii] = Bb[ii*256 + tid];

    #pragma unroll
    for (int jj = 0; jj < 8; ++jj) {
        const int row = w*8 + jj;
        const int jabs = half*32 + row;
        const size_t off = ((size_t)(b*L_SEQ + c*CHUNK + jabs)) * DIMSZ + h*ND + lane;
        const float qq = h2f(q[off]);
        float s, cc; sincosf(th * (float)jabs, &s, &cc);
        const float qhr = qq * cc, qhi = qq * s;
        QhR[row][lane] = (_Float16)qhr;
        QhI[row][lane] = (_Float16)qhi;
        QcR[row][lane]  = (_Float16)(qhr*cth_ - qhi*sth_);
        QcIn[row][lane] = (_Float16)(-(qhr*sth_ + qhi*cth_));
    }
    #pragma unroll
    for (int jj = 0; jj < 16; ++jj) {
        const int j = w*16 + jj;
        if (half == 0 && j >= 32) {
            VT[lane][j] = (_Float16)0.f;
        } else {
            const size_t off = ((size_t)(b*L_SEQ + c*CHUNK + j)) * DIMSZ + h*ND + lane;
            const float kk = h2f(k[off]), vv = h2f(v[off]);
            float s, cc; sincosf(th * (float)j, &s, &cc);
            KhR[j][lane] = (_Float16)(kk * cc);
            KhI[j][lane] = (_Float16)(kk * s);
            VT[lane][j]  = (_Float16)vv;
        }
    }
    __syncthreads();

    const f32x4 zf = {0.f, 0.f, 0.f, 0.f};
    f32x4 sacc[2] = {zf, zf};
    #pragma unroll
    for (int t = 0; t < 2; ++t) {
        const int nt = (w & 1)*2 + t;
        #pragma unroll
        for (int ks = 0; ks < 2; ++ks) {
            const f16x8 aR = *(const f16x8*)&QhR[mt*16 + rl][ks*32 + kg*8];
            const f16x8 bR = *(const f16x8*)&KhR[nt*16 + rl][ks*32 + kg*8];
            sacc[t] = __builtin_amdgcn_mfma_f32_16x16x32_f16(aR, bR, sacc[t], 0, 0, 0);
            const f16x8 aI = *(const f16x8*)&QhI[mt*16 + rl][ks*32 + kg*8];
            const f16x8 bI = *(const f16x8*)&KhI[nt*16 + rl][ks*32 + kg*8];
            sacc[t] = __builtin_amdgcn_mfma_f32_16x16x32_f16(aI, bI, sacc[t], 0, 0, 0);
        }
    }
    __syncthreads();

    #pragma unroll
    for (int t = 0; t < 2; ++t) {
        const int nt = (w & 1)*2 + t;
        #pragma unroll
        for (int r = 0; r < 4; ++r) {
            const int rowm = mt*16 + kg*4 + r;
            const int jabs = half*32 + rowm;
            const int jp = nt*16 + rl;
            const int delta = jabs - jp;
            const float val = (delta >= 0) ? sacc[t][r] * apw[delta] : 0.0f;
            SA[rowm][jp] = (_Float16)val;
        }
    }
    #pragma unroll
    for (int ii = 0; ii < 16; ++ii) {
        const int e = ii*4 + w;
        KhR[e][lane] = u2h((unsigned short)(breg[ii] & 0xffffu));
        KhI[e][lane] = u2h((unsigned short)(breg[ii] >> 16));
    }
    __syncthreads();

    #pragma unroll
    for (int t = 0; t < 2; ++t) {
        const int nt = (w & 1)*2 + t;
        f32x4 accO = zf, accC = zf;
        #pragma unroll
        for (int ks = 0; ks < 2; ++ks) {
            const f16x8 aS = *(const f16x8*)&SA[mt*16 + rl][ks*32 + kg*8];
            const f16x8 bV = *(const f16x8*)&VT[nt*16 + rl][ks*32 + kg*8];
            accO = __builtin_amdgcn_mfma_f32_16x16x32_f16(aS, bV, accO, 0, 0, 0);
            const f16x8 aCR = *(const f16x8*)&QcR[mt*16 + rl][ks*32 + kg*8];
            const f16x8 bBR = *(const f16x8*)&KhR[nt*16 + rl][ks*32 + kg*8];
            accC = __builtin_amdgcn_mfma_f32_16x16x32_f16(aCR, bBR, accC, 0, 0, 0);
            const f16x8 aCI = *(const f16x8*)&QcIn[mt*16 + rl][ks*32 + kg*8];
            const f16x8 bBI = *(const f16x8*)&KhI[nt*16 + rl][ks*32 + kg*8];
            accC = __builtin_amdgcn_mfma_f32_16x16x32_f16(aCI, bBI, accC, 0, 0, 0);
        }
        const int e = nt*16 + rl;
        #pragma unroll
        for (int r = 0; r < 4; ++r) {
            const int rowm = mt*16 + kg*4 + r;
            const int jabs = half*32 + rowm;
            const float cs = apw[jabs + 1];
            out[((size_t)(b*L_SEQ + c*CHUNK + jabs)) * DIMSZ + h*ND + e] =
                accO[r] + cs * accC[r];
        }
    }
}

// ---------------------------------------------------------------------------
extern "C" void kernel_launch(void* const* d_in, const int* in_sizes, int n_in,
                              void* d_out, int out_size, void* d_ws, size_t ws_size,
                              hipStream_t stream)
{
    const float* x     = (const float*)d_in[0];
    const float* wq_w  = (const float*)d_in[1];
    const float* wq_b  = (const float*)d_in[2];
    const float* wk_w  = (const float*)d_in[3];
    const float* wk_b  = (const float*)d_in[4];
    const float* wv_w  = (const float*)d_in[5];
    const float* wv_b  = (const float*)d_in[6];
    const float* ph_re = (const float*)d_in[7];
    const float* ph_im = (const float*)d_in[8];
    const float* ampl  = (const float*)d_in[9];
    const float* lc_re = (const float*)d_in[10];
    const float* lc_im = (const float*)d_in[11];
    float* out = (float*)d_out;

    char* wsb = (char*)d_ws;
    const size_t MB = 1024 * 1024;
    unsigned short* q = (unsigned short*)(wsb + 0);          // 2 MB (fp16)
    unsigned short* k = (unsigned short*)(wsb + 2 * MB);     // 2 MB
    unsigned short* v = (unsigned short*)(wsb + 4 * MB);     // 2 MB
    unsigned* kvB = (unsigned*)(wsb + 8 * MB);               // 4 MB (packed h2)
    unsigned short* Apk = (unsigned short*)(wsb + 13 * MB);  // 2 MB
    unsigned short* Bpk = (unsigned short*)(wsb + 16 * MB);  // 1.5 MB
    unsigned* lcT = (unsigned*)(wsb + 18 * MB);              // 128 KB

    pack_kernel<<<1800, 256, 0, stream>>>(
        x, wq_w, wk_w, wv_w, lc_re, lc_im, Apk, Bpk, lcT);
    gemm_kv_kernel<<<384, 256, 0, stream>>>(
        Apk, Bpk, wq_b, wk_b, wv_b, ph_re, ph_im, ampl, q, k, v, kvB);
    scan_kernel<<<256, 256, 0, stream>>>(kvB, lcT, ph_re, ph_im, ampl);
    chunk_out_kernel<<<BHTOT * NC * 2, 256, 0, stream>>>(
        q, k, v, kvB, ph_re, ph_im, ampl, out);
}

// Round 14
// 38.079 us; speedup vs baseline: 1.3070x; 1.0860x over previous
//
#include <hip/hip_runtime.h>
#include <hip/hip_bf16.h>
#include <math.h>

#define L_SEQ 1024
#define DIMSZ 512
#define NH 8
#define ND 64
#define NB 2
#define CHUNK 64
#define NC (L_SEQ / CHUNK)   // 16
#define BHTOT (NB * NH)      // 16
#define MTOT 2048
#define KEFF 512
#define BM 64
#define BN 128

typedef __attribute__((ext_vector_type(8))) _Float16 f16x8;
typedef __attribute__((ext_vector_type(4))) float f32x4;

#define GLD16(g, l) __builtin_amdgcn_global_load_lds( \
    (const __attribute__((address_space(1))) unsigned int*)(g), \
    (__attribute__((address_space(3))) unsigned int*)(l), 16, 0, 0)

__device__ static inline unsigned short f2h(float f) {
    union { _Float16 h; unsigned short u; } x;
    x.h = (_Float16)f;
    return x.u;
}
__device__ static inline float h2f(unsigned short u) {
    union { unsigned short u; _Float16 h; } x;
    x.u = u;
    return (float)x.h;
}
__device__ static inline unsigned packh2(float a, float b) {
    return (unsigned)f2h(a) | ((unsigned)f2h(b) << 16);
}

// ---------------------------------------------------------------------------
// pack: [0,1024)    A[n][k] = fp16(x)                    (2048 x 512)
//       [1024,1792) B~ rows: q -> o ; k/v -> 512+(o>>6)*128+(which-1)*64+(o&63)
//       [1792,1800) lcT[h][e*64+d] = packh2(lc[h][d][e])
// ---------------------------------------------------------------------------
__global__ __launch_bounds__(256) void pack_kernel(
    const float* __restrict__ x,
    const float* __restrict__ wq, const float* __restrict__ wk, const float* __restrict__ wv,
    const float* __restrict__ lc_re, const float* __restrict__ lc_im,
    unsigned short* __restrict__ A, unsigned short* __restrict__ Bm,
    unsigned* __restrict__ lcT)
{
    __shared__ unsigned T[64][65];
    const int bid = blockIdx.x;
    const int tid = threadIdx.x;
    if (bid < 1024) {
        const int i = bid * 256 + tid;
        const int n  = i >> 7;
        const int kq = (i & 127) << 2;
        const float4 xv = *(const float4*)(x + (size_t)n * DIMSZ + kq);
        *(ushort4*)(A + (size_t)n * KEFF + kq) =
            make_ushort4(f2h(xv.x), f2h(xv.y), f2h(xv.z), f2h(xv.w));
    } else if (bid < 1792) {
        const int idx = bid - 1024;
        const int which = idx >> 8;
        const float* w = which == 0 ? wq : (which == 1 ? wk : wv);
        const int i = (idx & 255) * 256 + tid;
        const int o  = i >> 7;
        const int kq = (i & 127) << 2;
        const float4 wv4 = *(const float4*)(w + (size_t)o * DIMSZ + kq);
        const int row = (which == 0) ? o
                      : 512 + (which - 1) * 64 + (o >> 6) * 128 + (o & 63);
        *(ushort4*)(Bm + (size_t)row * KEFF + kq) =
            make_ushort4(f2h(wv4.x), f2h(wv4.y), f2h(wv4.z), f2h(wv4.w));
    } else {
        const int h = bid - 1792;
        const int e = tid & 63;
        #pragma unroll
        for (int i = 0; i < 16; ++i) {
            const int d = i*4 + (tid >> 6);
            T[e][d] = packh2(lc_re[h*4096 + d*64 + e], lc_im[h*4096 + d*64 + e]);
        }
        __syncthreads();
        const int d = tid & 63;
        #pragma unroll
        for (int i = 0; i < 16; ++i) {
            const int e2 = i*4 + (tid >> 6);
            lcT[h*4096 + e2*64 + d] = T[e2][d];
        }
    }
}

// ---------------------------------------------------------------------------
// gemm_kv: 384 blocks.  sw<128: q-block.  sw>=128: [k|v]-block for (mtile,h)
// + fused chunk_kv (LDS overlay, incremental rotation/decay, MFMA KV^T).
// ---------------------------------------------------------------------------
__global__ __launch_bounds__(256) void gemm_kv_kernel(
    const unsigned short* __restrict__ A, const unsigned short* __restrict__ Bm,
    const float* __restrict__ bq, const float* __restrict__ bk, const float* __restrict__ bv,
    const float* __restrict__ ph_re, const float* __restrict__ ph_im,
    const float* __restrict__ ampl,
    unsigned short* __restrict__ qo, unsigned short* __restrict__ ko,
    unsigned short* __restrict__ vo, unsigned* __restrict__ kvB)
{
    __shared__ __align__(16) char lds[49152];   // gemm: 2 x [A 8KB | B 16KB]
    const int tid  = threadIdx.x;
    const int lane = tid & 63;
    const int wave = tid >> 6;

    const int bid0 = blockIdx.x;                 // 384 = 8 XCD x 48
    const int sw = (bid0 & 7) * 48 + (bid0 >> 3);
    const bool isQ = sw < 128;
    int mtile, brow0, h = 0, panel = 0;
    if (isQ) { panel = sw & 3; mtile = sw >> 2; brow0 = panel * 128; }
    else     { const int r = sw - 128; h = r & 7; mtile = r >> 3; brow0 = 512 + h * 128; }
    const int row0 = mtile * 64;
    const int wr = wave >> 1, wc = wave & 1;     // wave tile 32 x 64

    const int srow = tid >> 3;
    const int sin  = (tid & 7) << 4;
    size_t goffA[2], goffB[4];
    #pragma unroll
    for (int c = 0; c < 2; ++c) {
        const int row = c * 32 + srow;
        const int swz = sin ^ ((row & 7) << 4);
        goffA[c] = (size_t)(row0 + row) * (KEFF * 2) + swz;
    }
    #pragma unroll
    for (int c = 0; c < 4; ++c) {
        const int row = c * 32 + srow;
        const int swz = sin ^ ((row & 7) << 4);
        goffB[c] = (size_t)(brow0 + row) * (KEFF * 2) + swz;
    }
    const int ldst = tid * 16;
    const char* Abyte = (const char*)A;
    const char* Bbyte = (const char*)Bm;

    f32x4 acc[2][4];
    const f32x4 zf = {0.f, 0.f, 0.f, 0.f};
    #pragma unroll
    for (int m = 0; m < 2; ++m)
        #pragma unroll
        for (int n = 0; n < 4; ++n) acc[m][n] = zf;

    auto stage = [&](int buf, int t) {
        char* la = lds + buf * 24576;
        char* lb = la + 8192;
        const size_t kb = (size_t)t * 128;
        #pragma unroll
        for (int c = 0; c < 2; ++c)
            GLD16(Abyte + goffA[c] + kb, la + c * 4096 + ldst);
        #pragma unroll
        for (int c = 0; c < 4; ++c)
            GLD16(Bbyte + goffB[c] + kb, lb + c * 4096 + ldst);
    };

    const int rl = lane & 15;
    const int kg = lane >> 4;
    const int rswz = (rl & 7) << 4;

    auto compute = [&](int buf) {
        const char* la = lds + buf * 24576;
        const char* lb = la + 8192;
        #pragma unroll
        for (int ks = 0; ks < 2; ++ks) {
            f16x8 av[2], bvv[4];
            #pragma unroll
            for (int m = 0; m < 2; ++m) {
                const int row = wr * 32 + m * 16 + rl;
                const int addr = (row * 128 + ks * 64 + kg * 16) ^ rswz;
                av[m] = *(const f16x8*)(la + addr);
            }
            #pragma unroll
            for (int n = 0; n < 4; ++n) {
                const int row = wc * 64 + n * 16 + rl;
                const int addr = (row * 128 + ks * 64 + kg * 16) ^ rswz;
                bvv[n] = *(const f16x8*)(lb + addr);
            }
            #pragma unroll
            for (int m = 0; m < 2; ++m)
                #pragma unroll
                for (int n = 0; n < 4; ++n)
                    acc[m][n] = __builtin_amdgcn_mfma_f32_16x16x32_f16(
                        av[m], bvv[n], acc[m][n], 0, 0, 0);
        }
    };

    stage(0, 0);
    __syncthreads();
    const int NT = KEFF / 64;   // 8
    for (int t = 0; t < NT; ++t) {
        if (t + 1 < NT) stage((t + 1) & 1, t + 1);
        compute(t & 1);
        __syncthreads();
    }
    // all GEMM LDS dead from here on

    if (isQ) {
        #pragma unroll
        for (int n = 0; n < 4; ++n) {
            const int cabs = panel * 128 + wc * 64 + n * 16 + rl;
            const float bs = bq[cabs];
            #pragma unroll
            for (int m = 0; m < 2; ++m) {
                const int rb = row0 + wr * 32 + m * 16 + kg * 4;
                #pragma unroll
                for (int r = 0; r < 4; ++r)
                    qo[(size_t)(rb + r) * DIMSZ + cabs] = f2h(acc[m][n][r] + bs);
            }
        }
        return;
    }

    // ---- kv-block epilogue: global store + raw LDS stage (overlay) ----
    _Float16 (*KTR)[72] = (_Float16(*)[72])(lds);            //  9216 B
    _Float16 (*KTI)[72] = (_Float16(*)[72])(lds + 9216);     //  9216 B
    _Float16 (*VWT)[72] = (_Float16(*)[72])(lds + 18432);    //  9216 B

    unsigned short* outp = wc == 0 ? ko : vo;
    _Float16 (*RAW)[72] = wc == 0 ? KTR : VWT;   // raw k -> KTR, raw v -> VWT
    #pragma unroll
    for (int n = 0; n < 4; ++n) {
        const int cl = h * 64 + n * 16 + rl;
        const float bs = (wc == 0 ? bk : bv)[cl];
        #pragma unroll
        for (int m = 0; m < 2; ++m) {
            const int jb = wr * 32 + m * 16 + kg * 4;
            #pragma unroll
            for (int r = 0; r < 4; ++r) {
                const float val = acc[m][n][r] + bs;
                outp[(size_t)(row0 + jb + r) * DIMSZ + cl] = f2h(val);
                RAW[n * 16 + rl][jb + r] = (_Float16)val;    // [d or e][j]
            }
        }
    }
    __syncthreads();

    // ---- rotate/decay (incremental: j descending -> p ascending) ----
    const float amp = 1.0f / (1.0f + expf(-ampl[h]));
    const float la_ = logf(amp);
    const float th = atan2f(ph_im[h*ND + lane], ph_re[h*ND + lane]);
    float sth2, cth2; sincosf(th, &sth2, &cth2);
    const float p0 = (float)(CHUNK - 1 - (wave*16 + 15));
    float ap = expf(la_ * p0);
    float sp, cp; sincosf(th * p0, &sp, &cp);
    #pragma unroll
    for (int jj = 15; jj >= 0; --jj) {
        const int j = wave*16 + jj;
        const float kk = (float)KTR[lane][j];
        const float vv = (float)VWT[lane][j];
        KTR[lane][j] = (_Float16)(kk * cp);
        KTI[lane][j] = (_Float16)(kk * sp);
        VWT[lane][j] = (_Float16)(vv * ap);
        const float ncp = cp*cth2 - sp*sth2;          // p += 1
        sp = cp*sth2 + sp*cth2; cp = ncp;
        ap *= amp;
    }
    __syncthreads();

    // ---- KV^T MFMA + packed kvB store ----
    const int b = mtile >> 4, c = mtile & 15;
    unsigned* dst = kvB + (size_t)(((b * NH + h) << 4) | c) * (ND * ND);
    #pragma unroll
    for (int i = 0; i < 4; ++i) {
        const int mt = wave, nt = i;         // e-tile = wave, d-tile = i
        f32x4 aR = zf, aI = zf;
        #pragma unroll
        for (int ks = 0; ks < 2; ++ks) {
            const f16x8 av = *(const f16x8*)&VWT[mt*16 + rl][ks*32 + kg*8];
            const f16x8 br = *(const f16x8*)&KTR[nt*16 + rl][ks*32 + kg*8];
            const f16x8 bi = *(const f16x8*)&KTI[nt*16 + rl][ks*32 + kg*8];
            aR = __builtin_amdgcn_mfma_f32_16x16x32_f16(av, br, aR, 0, 0, 0);
            aI = __builtin_amdgcn_mfma_f32_16x16x32_f16(av, bi, aI, 0, 0, 0);
        }
        const int d = nt*16 + rl;
        #pragma unroll
        for (int r = 0; r < 4; ++r) {
            const int e = mt*16 + kg*4 + r;
            dst[e*ND + d] = packh2(aR[r], aI[r]);
        }
    }
}

// ---------------------------------------------------------------------------
// scan (packed fp16, transposed layout, coalesced packed lcT): idx = e*64+d.
// ---------------------------------------------------------------------------
__global__ __launch_bounds__(256) void scan_kernel(
    unsigned* __restrict__ kvB, const unsigned* __restrict__ lcT,
    const float* __restrict__ ph_re, const float* __restrict__ ph_im,
    const float* __restrict__ ampl)
{
    const int gid = blockIdx.x * 256 + threadIdx.x;   // 65536
    const int bh = gid >> 12;
    const int idx = gid & 4095;
    const int h = bh & 7;
    const int d = idx & 63;

    const float th = atan2f(ph_im[h*ND + d], ph_re[h*ND + d]);
    const float la = -logf(1.0f + expf(-ampl[h]));
    const float ampC = expf(la * (float)CHUNK);
    float s, ct; sincosf(th * (float)CHUNK, &s, &ct);
    const float aCr = ampC * ct, aCi = ampC * s;

    unsigned* base = kvB + (size_t)bh * NC * (ND*ND) + idx;
    unsigned tl[NC];
    #pragma unroll
    for (int cc = 0; cc < NC; ++cc) tl[cc] = base[(size_t)cc * (ND*ND)];

    const unsigned lcp = lcT[h*4096 + idx];
    float Sr = h2f((unsigned short)(lcp & 0xffffu));
    float Si = h2f((unsigned short)(lcp >> 16));
    #pragma unroll
    for (int cc = 0; cc < NC; ++cc) {
        base[(size_t)cc * (ND*ND)] = packh2(Sr, Si);
        const float tr = h2f((unsigned short)(tl[cc] & 0xffffu));
        const float ti = h2f((unsigned short)(tl[cc] >> 16));
        const float nr = aCr*Sr - aCi*Si + tr;
        const float ni = aCr*Si + aCi*Sr + ti;
        Sr = nr; Si = ni;
    }
}

// ---------------------------------------------------------------------------
// chunk_out (MFMA): 512 blocks (bhc*2+half), 32 output rows each.
// Incremental rotation (3 sincos/thread); cross-rotation folded into B at
// staging (B' = e^{i theta_d} B, stored as [B'R | -B'I]) -> Qc arrays gone.
// ---------------------------------------------------------------------------
__global__ __launch_bounds__(256) void chunk_out_kernel(
    const unsigned short* __restrict__ q, const unsigned short* __restrict__ k,
    const unsigned short* __restrict__ v, const unsigned* __restrict__ Bst,
    const float* __restrict__ ph_re, const float* __restrict__ ph_im,
    const float* __restrict__ ampl, float* __restrict__ out)
{
    __shared__ __align__(16) _Float16 QhR[32][72], QhI[32][72];
    __shared__ __align__(16) _Float16 KhR[64][72], KhI[64][72];   // -> B'R/-B'I
    __shared__ __align__(16) _Float16 VT[64][72];
    __shared__ __align__(16) _Float16 SA[32][72];
    __shared__ float apw[80];

    const int half = blockIdx.x & 1;
    const int bhc = blockIdx.x >> 1;
    const int c  = bhc & (NC - 1);
    const int bh = bhc >> 4;
    const int b = bh >> 3, h = bh & 7;
    const int tid = threadIdx.x;
    const int lane = tid & 63, w = tid >> 6;
    const int rl = lane & 15, kg = lane >> 4;
    const int mt = w >> 1;

    const float la = -logf(1.0f + expf(-ampl[h]));
    if (tid < 72) apw[tid] = expf(la * (float)tid);
    const float th = atan2f(ph_im[h*ND + lane], ph_re[h*ND + lane]);
    float sth_, cth_; sincosf(th, &sth_, &cth_);

    unsigned breg[16];
    const unsigned* Bb = Bst + (size_t)bhc * (ND*ND);
    #pragma unroll
    for (int ii = 0; ii < 16; ++ii) breg[ii] = Bb[ii*256 + tid];

    // ---- Q staging (incremental rotation from jbase) ----
    {
        const int jbase = half*32 + w*8;
        float sr, cr; sincosf(th * (float)jbase, &sr, &cr);
        #pragma unroll
        for (int jj = 0; jj < 8; ++jj) {
            const int row = w*8 + jj;
            const int jabs = jbase + jj;
            const size_t off = ((size_t)(b*L_SEQ + c*CHUNK + jabs)) * DIMSZ + h*ND + lane;
            const float qq = h2f(q[off]);
            QhR[row][lane] = (_Float16)(qq * cr);
            QhI[row][lane] = (_Float16)(qq * sr);
            const float ncr = cr*cth_ - sr*sth_;
            sr = cr*sth_ + sr*cth_; cr = ncr;
        }
    }
    // ---- K/V staging (incremental rotation from kbase) ----
    {
        const int kbase = w*16;
        float skr, ckr; sincosf(th * (float)kbase, &skr, &ckr);
        #pragma unroll
        for (int jj = 0; jj < 16; ++jj) {
            const int j = kbase + jj;
            if (half == 0 && j >= 32) {
                VT[lane][j] = (_Float16)0.f;   // KhR/KhI garbage masked later
            } else {
                const size_t off = ((size_t)(b*L_SEQ + c*CHUNK + j)) * DIMSZ + h*ND + lane;
                const float kk = h2f(k[off]), vv = h2f(v[off]);
                KhR[j][lane] = (_Float16)(kk * ckr);
                KhI[j][lane] = (_Float16)(kk * skr);
                VT[lane][j]  = (_Float16)vv;
            }
            const float nck = ckr*cth_ - skr*sth_;
            skr = ckr*sth_ + skr*cth_; ckr = nck;
        }
    }
    __syncthreads();

    // ---- scores ----
    const f32x4 zf = {0.f, 0.f, 0.f, 0.f};
    f32x4 sacc[2] = {zf, zf};
    #pragma unroll
    for (int t = 0; t < 2; ++t) {
        const int nt = (w & 1)*2 + t;
        #pragma unroll
        for (int ks = 0; ks < 2; ++ks) {
            const f16x8 aR = *(const f16x8*)&QhR[mt*16 + rl][ks*32 + kg*8];
            const f16x8 bR = *(const f16x8*)&KhR[nt*16 + rl][ks*32 + kg*8];
            sacc[t] = __builtin_amdgcn_mfma_f32_16x16x32_f16(aR, bR, sacc[t], 0, 0, 0);
            const f16x8 aI = *(const f16x8*)&QhI[mt*16 + rl][ks*32 + kg*8];
            const f16x8 bI = *(const f16x8*)&KhI[nt*16 + rl][ks*32 + kg*8];
            sacc[t] = __builtin_amdgcn_mfma_f32_16x16x32_f16(aI, bI, sacc[t], 0, 0, 0);
        }
    }
    __syncthreads();   // everyone done reading Kh

    // ---- SA = mask(scores) fp16;  B' = e^{i th_d} B -> Kh space ----
    #pragma unroll
    for (int t = 0; t < 2; ++t) {
        const int nt = (w & 1)*2 + t;
        #pragma unroll
        for (int r = 0; r < 4; ++r) {
            const int rowm = mt*16 + kg*4 + r;
            const int jabs = half*32 + rowm;
            const int jp = nt*16 + rl;
            const int delta = jabs - jp;
            const float val = (delta >= 0) ? sacc[t][r] * apw[delta] : 0.0f;
            SA[rowm][jp] = (_Float16)val;
        }
    }
    #pragma unroll
    for (int ii = 0; ii < 16; ++ii) {
        const int e = ii*4 + w;     // idx = ii*256 + tid -> e = ii*4 + w, d = lane
        const float br = h2f((unsigned short)(breg[ii] & 0xffffu));
        const float bi = h2f((unsigned short)(breg[ii] >> 16));
        KhR[e][lane] = (_Float16)(br*cth_ - bi*sth_);      //  B'R
        KhI[e][lane] = (_Float16)(-(br*sth_ + bi*cth_));   // -B'I
    }
    __syncthreads();

    // ---- PV + cross (cross uses Qh directly: Re(qhat . B')) ----
    #pragma unroll
    for (int t = 0; t < 2; ++t) {
        const int nt = (w & 1)*2 + t;
        f32x4 accO = zf, accC = zf;
        #pragma unroll
        for (int ks = 0; ks < 2; ++ks) {
            const f16x8 aS = *(const f16x8*)&SA[mt*16 + rl][ks*32 + kg*8];
            const f16x8 bV = *(const f16x8*)&VT[nt*16 + rl][ks*32 + kg*8];
            accO = __builtin_amdgcn_mfma_f32_16x16x32_f16(aS, bV, accO, 0, 0, 0);
            const f16x8 aR = *(const f16x8*)&QhR[mt*16 + rl][ks*32 + kg*8];
            const f16x8 bBR = *(const f16x8*)&KhR[nt*16 + rl][ks*32 + kg*8];
            accC = __builtin_amdgcn_mfma_f32_16x16x32_f16(aR, bBR, accC, 0, 0, 0);
            const f16x8 aI = *(const f16x8*)&QhI[mt*16 + rl][ks*32 + kg*8];
            const f16x8 bBI = *(const f16x8*)&KhI[nt*16 + rl][ks*32 + kg*8];
            accC = __builtin_amdgcn_mfma_f32_16x16x32_f16(aI, bBI, accC, 0, 0, 0);
        }
        const int e = nt*16 + rl;
        #pragma unroll
        for (int r = 0; r < 4; ++r) {
            const int rowm = mt*16 + kg*4 + r;
            const int jabs = half*32 + rowm;
            const float cs = apw[jabs + 1];
            out[((size_t)(b*L_SEQ + c*CHUNK + jabs)) * DIMSZ + h*ND + e] =
                accO[r] + cs * accC[r];
        }
    }
}

// ---------------------------------------------------------------------------
extern "C" void kernel_launch(void* const* d_in, const int* in_sizes, int n_in,
                              void* d_out, int out_size, void* d_ws, size_t ws_size,
                              hipStream_t stream)
{
    const float* x     = (const float*)d_in[0];
    const float* wq_w  = (const float*)d_in[1];
    const float* wq_b  = (const float*)d_in[2];
    const float* wk_w  = (const float*)d_in[3];
    const float* wk_b  = (const float*)d_in[4];
    const float* wv_w  = (const float*)d_in[5];
    const float* wv_b  = (const float*)d_in[6];
    const float* ph_re = (const float*)d_in[7];
    const float* ph_im = (const float*)d_in[8];
    const float* ampl  = (const float*)d_in[9];
    const float* lc_re = (const float*)d_in[10];
    const float* lc_im = (const float*)d_in[11];
    float* out = (float*)d_out;

    char* wsb = (char*)d_ws;
    const size_t MB = 1024 * 1024;
    unsigned short* q = (unsigned short*)(wsb + 0);          // 2 MB (fp16)
    unsigned short* k = (unsigned short*)(wsb + 2 * MB);     // 2 MB
    unsigned short* v = (unsigned short*)(wsb + 4 * MB);     // 2 MB
    unsigned* kvB = (unsigned*)(wsb + 8 * MB);               // 4 MB (packed h2)
    unsigned short* Apk = (unsigned short*)(wsb + 13 * MB);  // 2 MB
    unsigned short* Bpk = (unsigned short*)(wsb + 16 * MB);  // 1.5 MB
    unsigned* lcT = (unsigned*)(wsb + 18 * MB);              // 128 KB

    pack_kernel<<<1800, 256, 0, stream>>>(
        x, wq_w, wk_w, wv_w, lc_re, lc_im, Apk, Bpk, lcT);
    gemm_kv_kernel<<<384, 256, 0, stream>>>(
        Apk, Bpk, wq_b, wk_b, wv_b, ph_re, ph_im, ampl, q, k, v, kvB);
    scan_kernel<<<256, 256, 0, stream>>>(kvB, lcT, ph_re, ph_im, ampl);
    chunk_out_kernel<<<BHTOT * NC * 2, 256, 0, stream>>>(
        q, k, v, kvB, ph_re, ph_im, ampl, out);
}

// Round 15
// 32.277 us; speedup vs baseline: 1.5420x; 1.1798x over previous
//
#include <hip/hip_runtime.h>
#include <hip/hip_bf16.h>
#include <math.h>

#define L_SEQ 1024
#define DIMSZ 512
#define NH 8
#define ND 64
#define NB 2
#define CHUNK 64
#define NC (L_SEQ / CHUNK)   // 16
#define BHTOT (NB * NH)      // 16
#define MTOT 2048
#define KEFF 512
#define BM 64
#define BN 128

typedef __attribute__((ext_vector_type(8))) _Float16 f16x8;
typedef __attribute__((ext_vector_type(4))) float f32x4;

#define GLD16(g, l) __builtin_amdgcn_global_load_lds( \
    (const __attribute__((address_space(1))) unsigned int*)(g), \
    (__attribute__((address_space(3))) unsigned int*)(l), 16, 0, 0)

__device__ static inline unsigned short f2h(float f) {
    union { _Float16 h; unsigned short u; } x;
    x.h = (_Float16)f;
    return x.u;
}
__device__ static inline float h2f(unsigned short u) {
    union { unsigned short u; _Float16 h; } x;
    x.u = u;
    return (float)x.h;
}
__device__ static inline unsigned packh2(float a, float b) {
    return (unsigned)f2h(a) | ((unsigned)f2h(b) << 16);
}

// ---------------------------------------------------------------------------
// pack: [0,1024)    A[n][k] = fp16(x)                    (2048 x 512)
//       [1024,1792) B~ rows: q -> o ; k/v -> 512+(o>>6)*128+(which-1)*64+(o&63)
//       [1792,1800) lcT[h][e*64+d] = packh2(lc[h][d][e])
// ---------------------------------------------------------------------------
__global__ __launch_bounds__(256) void pack_kernel(
    const float* __restrict__ x,
    const float* __restrict__ wq, const float* __restrict__ wk, const float* __restrict__ wv,
    const float* __restrict__ lc_re, const float* __restrict__ lc_im,
    unsigned short* __restrict__ A, unsigned short* __restrict__ Bm,
    unsigned* __restrict__ lcT)
{
    __shared__ unsigned T[64][65];
    const int bid = blockIdx.x;
    const int tid = threadIdx.x;
    if (bid < 1024) {
        const int i = bid * 256 + tid;
        const int n  = i >> 7;
        const int kq = (i & 127) << 2;
        const float4 xv = *(const float4*)(x + (size_t)n * DIMSZ + kq);
        *(ushort4*)(A + (size_t)n * KEFF + kq) =
            make_ushort4(f2h(xv.x), f2h(xv.y), f2h(xv.z), f2h(xv.w));
    } else if (bid < 1792) {
        const int idx = bid - 1024;
        const int which = idx >> 8;
        const float* w = which == 0 ? wq : (which == 1 ? wk : wv);
        const int i = (idx & 255) * 256 + tid;
        const int o  = i >> 7;
        const int kq = (i & 127) << 2;
        const float4 wv4 = *(const float4*)(w + (size_t)o * DIMSZ + kq);
        const int row = (which == 0) ? o
                      : 512 + (which - 1) * 64 + (o >> 6) * 128 + (o & 63);
        *(ushort4*)(Bm + (size_t)row * KEFF + kq) =
            make_ushort4(f2h(wv4.x), f2h(wv4.y), f2h(wv4.z), f2h(wv4.w));
    } else {
        const int h = bid - 1792;
        const int e = tid & 63;
        #pragma unroll
        for (int i = 0; i < 16; ++i) {
            const int d = i*4 + (tid >> 6);
            T[e][d] = packh2(lc_re[h*4096 + d*64 + e], lc_im[h*4096 + d*64 + e]);
        }
        __syncthreads();
        const int d = tid & 63;
        #pragma unroll
        for (int i = 0; i < 16; ++i) {
            const int e2 = i*4 + (tid >> 6);
            lcT[h*4096 + e2*64 + d] = T[e2][d];
        }
    }
}

// ---------------------------------------------------------------------------
// gemm_kv: 384 blocks.  sw<128: q-block.  sw>=128: [k|v]-block for (mtile,h)
// + fused chunk_kv (LDS overlay, incremental rotation/decay, MFMA KV^T).
// ---------------------------------------------------------------------------
__global__ __launch_bounds__(256) void gemm_kv_kernel(
    const unsigned short* __restrict__ A, const unsigned short* __restrict__ Bm,
    const float* __restrict__ bq, const float* __restrict__ bk, const float* __restrict__ bv,
    const float* __restrict__ ph_re, const float* __restrict__ ph_im,
    const float* __restrict__ ampl,
    unsigned short* __restrict__ qo, unsigned short* __restrict__ ko,
    unsigned short* __restrict__ vo, unsigned* __restrict__ kvB)
{
    __shared__ __align__(16) char lds[49152];   // gemm: 2 x [A 8KB | B 16KB]
    const int tid  = threadIdx.x;
    const int lane = tid & 63;
    const int wave = tid >> 6;

    const int bid0 = blockIdx.x;                 // 384 = 8 XCD x 48
    const int sw = (bid0 & 7) * 48 + (bid0 >> 3);
    const bool isQ = sw < 128;
    int mtile, brow0, h = 0, panel = 0;
    if (isQ) { panel = sw & 3; mtile = sw >> 2; brow0 = panel * 128; }
    else     { const int r = sw - 128; h = r & 7; mtile = r >> 3; brow0 = 512 + h * 128; }
    const int row0 = mtile * 64;
    const int wr = wave >> 1, wc = wave & 1;     // wave tile 32 x 64

    const int srow = tid >> 3;
    const int sin  = (tid & 7) << 4;
    size_t goffA[2], goffB[4];
    #pragma unroll
    for (int c = 0; c < 2; ++c) {
        const int row = c * 32 + srow;
        const int swz = sin ^ ((row & 7) << 4);
        goffA[c] = (size_t)(row0 + row) * (KEFF * 2) + swz;
    }
    #pragma unroll
    for (int c = 0; c < 4; ++c) {
        const int row = c * 32 + srow;
        const int swz = sin ^ ((row & 7) << 4);
        goffB[c] = (size_t)(brow0 + row) * (KEFF * 2) + swz;
    }
    const int ldst = tid * 16;
    const char* Abyte = (const char*)A;
    const char* Bbyte = (const char*)Bm;

    f32x4 acc[2][4];
    const f32x4 zf = {0.f, 0.f, 0.f, 0.f};
    #pragma unroll
    for (int m = 0; m < 2; ++m)
        #pragma unroll
        for (int n = 0; n < 4; ++n) acc[m][n] = zf;

    auto stage = [&](int buf, int t) {
        char* la = lds + buf * 24576;
        char* lb = la + 8192;
        const size_t kb = (size_t)t * 128;
        #pragma unroll
        for (int c = 0; c < 2; ++c)
            GLD16(Abyte + goffA[c] + kb, la + c * 4096 + ldst);
        #pragma unroll
        for (int c = 0; c < 4; ++c)
            GLD16(Bbyte + goffB[c] + kb, lb + c * 4096 + ldst);
    };

    const int rl = lane & 15;
    const int kg = lane >> 4;
    const int rswz = (rl & 7) << 4;

    auto compute = [&](int buf) {
        const char* la = lds + buf * 24576;
        const char* lb = la + 8192;
        #pragma unroll
        for (int ks = 0; ks < 2; ++ks) {
            f16x8 av[2], bvv[4];
            #pragma unroll
            for (int m = 0; m < 2; ++m) {
                const int row = wr * 32 + m * 16 + rl;
                const int addr = (row * 128 + ks * 64 + kg * 16) ^ rswz;
                av[m] = *(const f16x8*)(la + addr);
            }
            #pragma unroll
            for (int n = 0; n < 4; ++n) {
                const int row = wc * 64 + n * 16 + rl;
                const int addr = (row * 128 + ks * 64 + kg * 16) ^ rswz;
                bvv[n] = *(const f16x8*)(lb + addr);
            }
            #pragma unroll
            for (int m = 0; m < 2; ++m)
                #pragma unroll
                for (int n = 0; n < 4; ++n)
                    acc[m][n] = __builtin_amdgcn_mfma_f32_16x16x32_f16(
                        av[m], bvv[n], acc[m][n], 0, 0, 0);
        }
    };

    stage(0, 0);
    __syncthreads();
    const int NT = KEFF / 64;   // 8
    for (int t = 0; t < NT; ++t) {
        if (t + 1 < NT) stage((t + 1) & 1, t + 1);
        compute(t & 1);
        __syncthreads();
    }
    // all GEMM LDS dead from here on

    if (isQ) {
        #pragma unroll
        for (int n = 0; n < 4; ++n) {
            const int cabs = panel * 128 + wc * 64 + n * 16 + rl;
            const float bs = bq[cabs];
            #pragma unroll
            for (int m = 0; m < 2; ++m) {
                const int rb = row0 + wr * 32 + m * 16 + kg * 4;
                #pragma unroll
                for (int r = 0; r < 4; ++r)
                    qo[(size_t)(rb + r) * DIMSZ + cabs] = f2h(acc[m][n][r] + bs);
            }
        }
        return;
    }

    // ---- kv-block epilogue: global store + raw LDS stage (overlay) ----
    _Float16 (*KTR)[72] = (_Float16(*)[72])(lds);            //  9216 B
    _Float16 (*KTI)[72] = (_Float16(*)[72])(lds + 9216);     //  9216 B
    _Float16 (*VWT)[72] = (_Float16(*)[72])(lds + 18432);    //  9216 B

    unsigned short* outp = wc == 0 ? ko : vo;
    _Float16 (*RAW)[72] = wc == 0 ? KTR : VWT;   // raw k -> KTR, raw v -> VWT
    #pragma unroll
    for (int n = 0; n < 4; ++n) {
        const int cl = h * 64 + n * 16 + rl;
        const float bs = (wc == 0 ? bk : bv)[cl];
        #pragma unroll
        for (int m = 0; m < 2; ++m) {
            const int jb = wr * 32 + m * 16 + kg * 4;
            #pragma unroll
            for (int r = 0; r < 4; ++r) {
                const float val = acc[m][n][r] + bs;
                outp[(size_t)(row0 + jb + r) * DIMSZ + cl] = f2h(val);
                RAW[n * 16 + rl][jb + r] = (_Float16)val;    // [d or e][j]
            }
        }
    }
    __syncthreads();

    // ---- rotate/decay (incremental: j descending -> p ascending) ----
    const float amp = 1.0f / (1.0f + expf(-ampl[h]));
    const float la_ = logf(amp);
    const float th = atan2f(ph_im[h*ND + lane], ph_re[h*ND + lane]);
    float sth2, cth2; sincosf(th, &sth2, &cth2);
    const float p0 = (float)(CHUNK - 1 - (wave*16 + 15));
    float ap = expf(la_ * p0);
    float sp, cp; sincosf(th * p0, &sp, &cp);
    #pragma unroll
    for (int jj = 15; jj >= 0; --jj) {
        const int j = wave*16 + jj;
        const float kk = (float)KTR[lane][j];
        const float vv = (float)VWT[lane][j];
        KTR[lane][j] = (_Float16)(kk * cp);
        KTI[lane][j] = (_Float16)(kk * sp);
        VWT[lane][j] = (_Float16)(vv * ap);
        const float ncp = cp*cth2 - sp*sth2;          // p += 1
        sp = cp*sth2 + sp*cth2; cp = ncp;
        ap *= amp;
    }
    __syncthreads();

    // ---- KV^T MFMA + packed kvB store ----
    const int b = mtile >> 4, c = mtile & 15;
    unsigned* dst = kvB + (size_t)(((b * NH + h) << 4) | c) * (ND * ND);
    #pragma unroll
    for (int i = 0; i < 4; ++i) {
        const int mt = wave, nt = i;         // e-tile = wave, d-tile = i
        f32x4 aR = zf, aI = zf;
        #pragma unroll
        for (int ks = 0; ks < 2; ++ks) {
            const f16x8 av = *(const f16x8*)&VWT[mt*16 + rl][ks*32 + kg*8];
            const f16x8 br = *(const f16x8*)&KTR[nt*16 + rl][ks*32 + kg*8];
            const f16x8 bi = *(const f16x8*)&KTI[nt*16 + rl][ks*32 + kg*8];
            aR = __builtin_amdgcn_mfma_f32_16x16x32_f16(av, br, aR, 0, 0, 0);
            aI = __builtin_amdgcn_mfma_f32_16x16x32_f16(av, bi, aI, 0, 0, 0);
        }
        const int d = nt*16 + rl;
        #pragma unroll
        for (int r = 0; r < 4; ++r) {
            const int e = mt*16 + kg*4 + r;
            dst[e*ND + d] = packh2(aR[r], aI[r]);
        }
    }
}

// ---------------------------------------------------------------------------
// scan (packed fp16, transposed layout, coalesced packed lcT): idx = e*64+d.
// ---------------------------------------------------------------------------
__global__ __launch_bounds__(256) void scan_kernel(
    unsigned* __restrict__ kvB, const unsigned* __restrict__ lcT,
    const float* __restrict__ ph_re, const float* __restrict__ ph_im,
    const float* __restrict__ ampl)
{
    const int gid = blockIdx.x * 256 + threadIdx.x;   // 65536
    const int bh = gid >> 12;
    const int idx = gid & 4095;
    const int h = bh & 7;
    const int d = idx & 63;

    const float th = atan2f(ph_im[h*ND + d], ph_re[h*ND + d]);
    const float la = -logf(1.0f + expf(-ampl[h]));
    const float ampC = expf(la * (float)CHUNK);
    float s, ct; sincosf(th * (float)CHUNK, &s, &ct);
    const float aCr = ampC * ct, aCi = ampC * s;

    unsigned* base = kvB + (size_t)bh * NC * (ND*ND) + idx;
    unsigned tl[NC];
    #pragma unroll
    for (int cc = 0; cc < NC; ++cc) tl[cc] = base[(size_t)cc * (ND*ND)];

    const unsigned lcp = lcT[h*4096 + idx];
    float Sr = h2f((unsigned short)(lcp & 0xffffu));
    float Si = h2f((unsigned short)(lcp >> 16));
    #pragma unroll
    for (int cc = 0; cc < NC; ++cc) {
        base[(size_t)cc * (ND*ND)] = packh2(Sr, Si);
        const float tr = h2f((unsigned short)(tl[cc] & 0xffffu));
        const float ti = h2f((unsigned short)(tl[cc] >> 16));
        const float nr = aCr*Sr - aCi*Si + tr;
        const float ni = aCr*Si + aCi*Sr + ti;
        Sr = nr; Si = ni;
    }
}

// ---------------------------------------------------------------------------
// chunk_out (MFMA): ONE 512-thread block per (b,h,c); 8 waves; 64 output
// rows.  Wave w owns row-tile rt=w>>1, col-tiles nt=(w&1)*2+{0,1}.  Fully
// causal-masked score tiles (rt<nt) skip their MFMAs.  B staged once.
// ---------------------------------------------------------------------------
__global__ __launch_bounds__(512) void chunk_out_kernel(
    const unsigned short* __restrict__ q, const unsigned short* __restrict__ k,
    const unsigned short* __restrict__ v, const unsigned* __restrict__ Bst,
    const float* __restrict__ ph_re, const float* __restrict__ ph_im,
    const float* __restrict__ ampl, float* __restrict__ out)
{
    __shared__ __align__(16) _Float16 QhR[64][72], QhI[64][72];
    __shared__ __align__(16) _Float16 KhR[64][72], KhI[64][72];   // -> B'R/-B'I
    __shared__ __align__(16) _Float16 VT[64][72];
    __shared__ __align__(16) _Float16 SA[64][72];
    __shared__ float apw[80];

    const int bhc = blockIdx.x;
    const int c  = bhc & (NC - 1);
    const int bh = bhc >> 4;
    const int b = bh >> 3, h = bh & 7;
    const int tid = threadIdx.x;
    const int lane = tid & 63, w = tid >> 6;
    const int rl = lane & 15, kg = lane >> 4;
    const int rt = w >> 1;                        // row-tile (0..3)

    const float la = -logf(1.0f + expf(-ampl[h]));
    if (tid < 72) apw[tid] = expf(la * (float)tid);
    const float th = atan2f(ph_im[h*ND + lane], ph_re[h*ND + lane]);
    float sth_, cth_; sincosf(th, &sth_, &cth_);

    // early B-state loads (8 per thread; idx = ii*512 + tid -> e = ii*8+w)
    unsigned breg[8];
    const unsigned* Bb = Bst + (size_t)bhc * (ND*ND);
    #pragma unroll
    for (int ii = 0; ii < 8; ++ii) breg[ii] = Bb[ii*512 + tid];

    // ---- Q + K/V staging (8 rows per wave, incremental rotation) ----
    {
        const int jbase = w * 8;
        float sr, cr; sincosf(th * (float)jbase, &sr, &cr);
        #pragma unroll
        for (int jj = 0; jj < 8; ++jj) {
            const int j = jbase + jj;
            const size_t off = ((size_t)(b*L_SEQ + c*CHUNK + j)) * DIMSZ + h*ND + lane;
            const float qq = h2f(q[off]);
            const float kk = h2f(k[off]);
            QhR[j][lane] = (_Float16)(qq * cr);
            QhI[j][lane] = (_Float16)(qq * sr);
            KhR[j][lane] = (_Float16)(kk * cr);
            KhI[j][lane] = (_Float16)(kk * sr);
            VT[lane][j]  = (_Float16)h2f(v[off]);
            const float ncr = cr*cth_ - sr*sth_;
            sr = cr*sth_ + sr*cth_; cr = ncr;
        }
    }
    __syncthreads();

    // ---- scores (skip fully-masked tiles rt < nt) ----
    const f32x4 zf = {0.f, 0.f, 0.f, 0.f};
    f32x4 sacc[2] = {zf, zf};
    #pragma unroll
    for (int t = 0; t < 2; ++t) {
        const int nt = (w & 1)*2 + t;
        if (rt >= nt) {
            #pragma unroll
            for (int ks = 0; ks < 2; ++ks) {
                const f16x8 aR = *(const f16x8*)&QhR[rt*16 + rl][ks*32 + kg*8];
                const f16x8 bR = *(const f16x8*)&KhR[nt*16 + rl][ks*32 + kg*8];
                sacc[t] = __builtin_amdgcn_mfma_f32_16x16x32_f16(aR, bR, sacc[t], 0, 0, 0);
                const f16x8 aI = *(const f16x8*)&QhI[rt*16 + rl][ks*32 + kg*8];
                const f16x8 bI = *(const f16x8*)&KhI[nt*16 + rl][ks*32 + kg*8];
                sacc[t] = __builtin_amdgcn_mfma_f32_16x16x32_f16(aI, bI, sacc[t], 0, 0, 0);
            }
        }
    }
    __syncthreads();   // everyone done reading Kh

    // ---- SA = mask(scores) fp16;  B' = e^{i th_d} B -> Kh space ----
    #pragma unroll
    for (int t = 0; t < 2; ++t) {
        const int nt = (w & 1)*2 + t;
        #pragma unroll
        for (int r = 0; r < 4; ++r) {
            const int rowm = rt*16 + kg*4 + r;
            const int jp = nt*16 + rl;
            const int delta = rowm - jp;
            const float val = (delta >= 0) ? sacc[t][r] * apw[delta] : 0.0f;
            SA[rowm][jp] = (_Float16)val;
        }
    }
    #pragma unroll
    for (int ii = 0; ii < 8; ++ii) {
        const int e = ii*8 + w;     // idx = ii*512 + tid -> e = ii*8 + w, d = lane
        const float br = h2f((unsigned short)(breg[ii] & 0xffffu));
        const float bi = h2f((unsigned short)(breg[ii] >> 16));
        KhR[e][lane] = (_Float16)(br*cth_ - bi*sth_);      //  B'R
        KhI[e][lane] = (_Float16)(-(br*sth_ + bi*cth_));   // -B'I
    }
    __syncthreads();

    // ---- PV + cross (cross uses Qh directly: Re(qhat . B')) ----
    #pragma unroll
    for (int t = 0; t < 2; ++t) {
        const int nt = (w & 1)*2 + t;
        f32x4 accO = zf, accC = zf;
        #pragma unroll
        for (int ks = 0; ks < 2; ++ks) {
            const f16x8 aS = *(const f16x8*)&SA[rt*16 + rl][ks*32 + kg*8];
            const f16x8 bV = *(const f16x8*)&VT[nt*16 + rl][ks*32 + kg*8];
            accO = __builtin_amdgcn_mfma_f32_16x16x32_f16(aS, bV, accO, 0, 0, 0);
            const f16x8 aR = *(const f16x8*)&QhR[rt*16 + rl][ks*32 + kg*8];
            const f16x8 bBR = *(const f16x8*)&KhR[nt*16 + rl][ks*32 + kg*8];
            accC = __builtin_amdgcn_mfma_f32_16x16x32_f16(aR, bBR, accC, 0, 0, 0);
            const f16x8 aI = *(const f16x8*)&QhI[rt*16 + rl][ks*32 + kg*8];
            const f16x8 bBI = *(const f16x8*)&KhI[nt*16 + rl][ks*32 + kg*8];
            accC = __builtin_amdgcn_mfma_f32_16x16x32_f16(aI, bBI, accC, 0, 0, 0);
        }
        const int e = nt*16 + rl;
        #pragma unroll
        for (int r = 0; r < 4; ++r) {
            const int rowm = rt*16 + kg*4 + r;
            const float cs = apw[rowm + 1];
            out[((size_t)(b*L_SEQ + c*CHUNK + rowm)) * DIMSZ + h*ND + e] =
                accO[r] + cs * accC[r];
        }
    }
}

// ---------------------------------------------------------------------------
extern "C" void kernel_launch(void* const* d_in, const int* in_sizes, int n_in,
                              void* d_out, int out_size, void* d_ws, size_t ws_size,
                              hipStream_t stream)
{
    const float* x     = (const float*)d_in[0];
    const float* wq_w  = (const float*)d_in[1];
    const float* wq_b  = (const float*)d_in[2];
    const float* wk_w  = (const float*)d_in[3];
    const float* wk_b  = (const float*)d_in[4];
    const float* wv_w  = (const float*)d_in[5];
    const float* wv_b  = (const float*)d_in[6];
    const float* ph_re = (const float*)d_in[7];
    const float* ph_im = (const float*)d_in[8];
    const float* ampl  = (const float*)d_in[9];
    const float* lc_re = (const float*)d_in[10];
    const float* lc_im = (const float*)d_in[11];
    float* out = (float*)d_out;

    char* wsb = (char*)d_ws;
    const size_t MB = 1024 * 1024;
    unsigned short* q = (unsigned short*)(wsb + 0);          // 2 MB (fp16)
    unsigned short* k = (unsigned short*)(wsb + 2 * MB);     // 2 MB
    unsigned short* v = (unsigned short*)(wsb + 4 * MB);     // 2 MB
    unsigned* kvB = (unsigned*)(wsb + 8 * MB);               // 4 MB (packed h2)
    unsigned short* Apk = (unsigned short*)(wsb + 13 * MB);  // 2 MB
    unsigned short* Bpk = (unsigned short*)(wsb + 16 * MB);  // 1.5 MB
    unsigned* lcT = (unsigned*)(wsb + 18 * MB);              // 128 KB

    pack_kernel<<<1800, 256, 0, stream>>>(
        x, wq_w, wk_w, wv_w, lc_re, lc_im, Apk, Bpk, lcT);
    gemm_kv_kernel<<<384, 256, 0, stream>>>(
        Apk, Bpk, wq_b, wk_b, wv_b, ph_re, ph_im, ampl, q, k, v, kvB);
    scan_kernel<<<256, 256, 0, stream>>>(kvB, lcT, ph_re, ph_im, ampl);
    chunk_out_kernel<<<BHTOT * NC, 512, 0, stream>>>(
        q, k, v, kvB, ph_re, ph_im, ampl, out);
}